// Round 10
// baseline (601.643 us; speedup 1.0000x reference)
//
#include <hip/hip_runtime.h>
#include <hip/hip_bf16.h>

// LightGCN on MI355X — round 19.
// R18: WIN (597.5, best). spmm frozen at 109us/VGPR20.
// R19 theory: bottom-up kernel-time estimate leaves ~200us unexplained ->
// dispatch overhead (~10us x 13 dispatches) dominates the non-spmm side.
// Cut 13 -> 9 dispatches with NO hot-loop changes:
//  (1) k_init = sniff (LDS-reduce, plain store) + btotal zeroing (kills memset)
//  (2) k_prep = stage_gather || count fused by block-range split
//  (3) delete both k_gacc: epilogue reads S1 (layer1) + S0 (layer2) batch rows
//      directly: out_final = (out + S1[row] + S0[row]) * 0.25
// Predict total 597.5 -> ~560-575; if <12us gain, launch-gap theory wrong.

#define DIM   64
#define FTHR  2048   // float sniff: >FTHR of 4096 words look bf16-packed
#define WTHR  512    // wide sniff:  >WTHR of 1024 odd words are zero -> int64
#define SHIFT 10
#define BSZ   (1 << SHIFT)     // 1024 dst rows per bucket
#define KMAX  1023             // scanB (1024 thr) handles up to 1023 buckets
#define CHUNK 16384            // edges per count/scat block
#define CTPB  512              // scat threads per block
#define SPT   (CHUNK / CTPB)   // 32 edges per thread in scat
#define STPB  512              // p2sort threads per block
#define SBT   1024             // scanB threads

__device__ __forceinline__ float bf2f(unsigned short u) {
    return __builtin_bit_cast(float, ((unsigned)u) << 16);
}
__device__ __forceinline__ unsigned short f2bf(float x) {
    return __builtin_bit_cast(unsigned short, __float2bfloat16(x));
}
__device__ __forceinline__ int idx_at(const void* a, long long i, int wide) {
    return wide ? (int)((const long long*)a)[i] : ((const int*)a)[i];
}
__device__ __forceinline__ int clampi(int v, int hi) {
    return v < 0 ? 0 : (v >= hi ? hi - 1 : v);
}

// ---- init: blocks 0-4 sniff -> flags[b] (plain store); blocks 5+ zero btotal
// flags: [0] ue float-kind [1] ie float-kind [2] eval float-kind
//        [3] edge idx wide [4] batch idx wide
__global__ void k_init(const unsigned* __restrict__ ue, const unsigned* __restrict__ ie,
                       const unsigned* __restrict__ eval, const unsigned* __restrict__ esrc,
                       const unsigned* __restrict__ users, int* __restrict__ flags,
                       int* __restrict__ btotal, int K) {
    int b = blockIdx.x, t = threadIdx.x;
    if (b < 5) {
        const unsigned* p = (b == 0) ? ue : (b == 1) ? ie : (b == 2) ? eval
                           : (b == 3) ? esrc : users;
        int cnt = 0;
        if (b < 3) {
            for (int i = t; i < 4096; i += 256) {
                unsigned e = (p[i] >> 7) & 0xffu;
                if (e >= 110u && e <= 135u) cnt++;
            }
        } else {
            for (int i = t; i < 1024; i += 256)
                if (p[2 * i + 1] == 0u) cnt++;
        }
        __shared__ int part[4];
        #pragma unroll
        for (int off = 32; off > 0; off >>= 1) cnt += __shfl_down(cnt, off, 64);
        if ((t & 63) == 0) part[t >> 6] = cnt;
        __syncthreads();
        if (t == 0) flags[b] = part[0] + part[1] + part[2] + part[3];
    } else {
        int i = (b - 5) * 256 + t;
        if (i <= K) btotal[i] = 0;
    }
}

// ---- prep: blocks [0,nStage) stage S0 + layer-0 gather; rest: bucket count
__global__ void k_prep(const void* __restrict__ ue, const void* __restrict__ ie,
                       const void* __restrict__ users, const void* __restrict__ items,
                       const void* __restrict__ edst,
                       ushort4* __restrict__ S, float* __restrict__ out,
                       int* __restrict__ btotal, const int* __restrict__ flags,
                       int NU16, int N16, int B, int NU, int NI,
                       int E, int N, int K, int nStage) {
    if (blockIdx.x < nStage) {
        int tid = blockIdx.x * blockDim.x + threadIdx.x;
        if (tid < N16) {
            // stage: one ushort4 (4 bf16) per thread
            bool user = tid < NU16;
            const void* src = user ? ue : ie;
            int fl  = user ? flags[0] : flags[1];
            int idx = user ? tid : tid - NU16;
            ushort4 o;
            if (fl > FTHR) {
                o = ((const ushort4*)src)[idx];
            } else {
                float4 v = ((const float4*)src)[idx];
                o.x = f2bf(v.x); o.y = f2bf(v.y); o.z = f2bf(v.z); o.w = f2bf(v.w);
            }
            S[tid] = o;
        } else {
            // layer-0 gather: out[slot] = input emb (f32)
            int g = tid - N16;
            int r = g >> 6, d = g & 63;
            if (r >= 2 * B) return;
            int wide = flags[4] > WTHR;
            const void* src; long long row; int fl;
            if (r < B) { row = clampi(idx_at(users, r, wide), NU); src = ue; fl = flags[0]; }
            else       { row = clampi(idx_at(items, r - B, wide), NI); src = ie; fl = flags[1]; }
            float v;
            if (fl > FTHR) v = bf2f(((const unsigned short*)src)[row * 64 + d]);
            else           v = ((const float*)src)[row * 64 + d];
            out[g] = v;
        }
    } else {
        // count: per-block LDS hist -> global atomic bucket totals
        __shared__ int h[KMAX + 1];
        int t = threadIdx.x;
        for (int i = t; i < K; i += blockDim.x) h[i] = 0;
        __syncthreads();
        int wide = flags[3] > WTHR;
        int base = (blockIdx.x - nStage) * CHUNK;
        int lim = min(base + CHUNK, E);
        for (int i = base + t; i < lim; i += blockDim.x) {
            int d = clampi(idx_at(edst, i, wide), N);
            atomicAdd(&h[d >> SHIFT], 1);
        }
        __syncthreads();
        for (int i = t; i < K; i += blockDim.x)
            if (h[i]) atomicAdd(&btotal[i], h[i]);
    }
}

// ---- scanB: bucket starts + init global cursors (1 block, 1024 thr) ----
__global__ __launch_bounds__(SBT) void k_scanB(const int* __restrict__ btotal,
                        int* __restrict__ bucketStart, int* __restrict__ gcur,
                        int* __restrict__ rowstart, int K, int N) {
    __shared__ int sh[SBT];
    int t = threadIdx.x;
    int v = (t < K) ? btotal[t] : 0;
    sh[t] = v;
    for (int off = 1; off < SBT; off <<= 1) {
        __syncthreads();
        int y = (t >= off) ? sh[t - off] : 0;
        __syncthreads();
        sh[t] += y;
    }
    __syncthreads();
    if (t <= K) bucketStart[t] = sh[t] - v;   // exclusive (t=K: v=0 -> total)
    if (t < K)  gcur[t] = sh[t] - v;
    if (t == SBT - 1) rowstart[N] = sh[SBT - 1];  // total edge count
}

// ---- scat: reserve bucket ranges dynamically, LDS-cursor scatter ----
// pass A stashes clamped d in registers (SPT=32/thread) so pass B skips edst.
__global__ __launch_bounds__(CTPB) void k_scat(const void* __restrict__ esrc,
                       const void* __restrict__ edst,
                       const void* __restrict__ eval, const int* __restrict__ flags,
                       int* __restrict__ gcur, unsigned long long* __restrict__ TMP,
                       int E, int N, int K) {
    __shared__ int h[KMAX + 1];
    __shared__ int cur[KMAX + 1];
    int t = threadIdx.x;
    for (int i = t; i < K; i += CTPB) h[i] = 0;
    __syncthreads();
    int wide = flags[3] > WTHR;
    int evalbf = flags[2] > FTHR;
    int base = blockIdx.x * CHUNK;
    int lim = min(base + CHUNK, E);
    // pass A: chunk histogram; stash d in registers (static indexing)
    int dstash[SPT];
    #pragma unroll
    for (int j = 0; j < SPT; ++j) {
        int i = base + t + j * CTPB;
        int d = 0;
        if (i < lim) {
            d = clampi(idx_at(edst, i, wide), N);
            atomicAdd(&h[d >> SHIFT], 1);
        }
        dstash[j] = d;
    }
    __syncthreads();
    // reserve contiguous ranges in each touched bucket
    for (int i = t; i < K; i += CTPB)
        if (h[i]) cur[i] = atomicAdd(&gcur[i], h[i]);
    __syncthreads();
    // pass B: scatter via LDS cursors (runs of ~56 edges/bucket = 448B)
    #pragma unroll
    for (int j = 0; j < SPT; ++j) {
        int i = base + t + j * CTPB;
        if (i >= lim) continue;
        int d = dstash[j];
        int s = clampi(idx_at(esrc, i, wide), N);
        unsigned short vb = evalbf ? ((const unsigned short*)eval)[i]
                                   : f2bf(((const float*)eval)[i]);
        int b = d >> SHIFT;
        unsigned dl = (unsigned)(d & (BSZ - 1));
        int slot = atomicAdd(&cur[b], 1);
        unsigned long long p = (unsigned long long)(unsigned)s
                             | (((unsigned long long)((dl << 16) | vb)) << 32);
        TMP[slot] = p;
    }
}

// ---- sort pass 2: in-bucket counting sort + rowstart (1 block/bucket, 512 thr)
__global__ __launch_bounds__(STPB) void k_p2sort(const unsigned long long* __restrict__ TMP,
                         const int* __restrict__ bucketStart,
                         int2* __restrict__ edges, int* __restrict__ rowstart,
                         int N) {
    __shared__ int hist[BSZ];
    __shared__ int wsum[STPB / 64];
    int b = blockIdx.x;
    int t = threadIdx.x;
    int span0 = bucketStart[b], span1 = bucketStart[b + 1];
    int rbase = b << SHIFT;
    int nrows = min(BSZ, N - rbase);
    for (int i = t; i < BSZ; i += STPB) hist[i] = 0;
    __syncthreads();
    for (int e = span0 + t; e < span1; e += STPB) {
        int dl = (int)((TMP[e] >> 48) & (BSZ - 1));
        atomicAdd(&hist[dl], 1);
    }
    __syncthreads();
    // block-wide exclusive prefix sum over BSZ entries, BSZ/STPB per thread
    const int PER = BSZ / STPB;   // 2
    int loc[PER];
    int s = 0;
    #pragma unroll
    for (int j = 0; j < PER; ++j) {
        int v = hist[t * PER + j];
        loc[j] = s;
        s += v;
    }
    int wid = t >> 6, lane = t & 63;
    int x = s;
    #pragma unroll
    for (int off = 1; off < 64; off <<= 1) {
        int y = __shfl_up(x, off, 64);
        if (lane >= off) x += y;
    }
    if (lane == 63) wsum[wid] = x;
    __syncthreads();
    int wbase = 0;
    #pragma unroll
    for (int w = 0; w < STPB / 64; ++w) wbase += (w < wid) ? wsum[w] : 0;
    int texcl = wbase + x - s;
    #pragma unroll
    for (int j = 0; j < PER; ++j) hist[t * PER + j] = texcl + loc[j];
    __syncthreads();
    // rowstart for this bucket's rows
    for (int r = t; r < nrows; r += STPB) rowstart[rbase + r] = span0 + hist[r];
    __syncthreads();
    // scatter to final sorted position (hist doubles as cursor)
    for (int e = span0 + t; e < span1; e += STPB) {
        unsigned long long p = TMP[e];
        int dl = (int)((p >> 48) & (BSZ - 1));
        unsigned vb = (unsigned)((p >> 32) & 0xffffu);
        int src = (int)(unsigned)p;
        int slot = span0 + atomicAdd(&hist[dl], 1);
        edges[slot] = make_int2(src, (int)(vb << 16));
    }
}

// ---- atomic-free SpMM body — k_spmm's private copy (R16 frozen form) ----
template <int U>
__device__ __forceinline__ void spmm_batchA(const unsigned short* __restrict__ Sin,
                                            const int2* __restrict__ edges,
                                            int k, int lane, float& acc) {
    int2 e[U];
    #pragma unroll
    for (int j = 0; j < U; ++j) e[j] = edges[k + j];
    float a[U];
    #pragma unroll
    for (int j = 0; j < U; ++j) a[j] = bf2f(Sin[(size_t)e[j].x * 64 + lane]);
    #pragma unroll
    for (int j = 0; j < U; ++j) acc += __int_as_float(e[j].y) * a[j];
}

// ---- full SpMM: one wave per dst row, lane = dim (FROZEN, do not touch) ----
__global__ void k_spmm(const unsigned short* __restrict__ Sin,
                       unsigned short* __restrict__ Sout,
                       const int* __restrict__ rowstart,
                       const int2* __restrict__ edges, int N) {
    int wid = (blockIdx.x * blockDim.x + threadIdx.x) >> 6;
    int lane = threadIdx.x & 63;
    if (wid >= N) return;
    int start = __builtin_amdgcn_readfirstlane(rowstart[wid]);
    int end   = __builtin_amdgcn_readfirstlane(rowstart[wid + 1]);
    float acc = 0.f;
    int k = start;
    for (; k + 16 <= end; k += 16) spmm_batchA<16>(Sin, edges, k, lane, acc);
    if (k + 8 <= end) { spmm_batchA<8>(Sin, edges, k, lane, acc); k += 8; }
    if (k + 4 <= end) { spmm_batchA<4>(Sin, edges, k, lane, acc); k += 4; }
    if (k + 2 <= end) { spmm_batchA<2>(Sin, edges, k, lane, acc); k += 2; }
    if (k < end)      { spmm_batchA<1>(Sin, edges, k, lane, acc); }
    __builtin_nontemporal_store(f2bf(acc), &Sout[(size_t)wid * 64 + lane]);
}

// ---- k_spmm_b's private copy of the body (codegen isolation) ----
template <int U>
__device__ __forceinline__ void spmm_batchB(const unsigned short* __restrict__ Sin,
                                            const int2* __restrict__ edges,
                                            int k, int lane, float& acc) {
    int2 e[U];
    #pragma unroll
    for (int j = 0; j < U; ++j) e[j] = edges[k + j];
    float a[U];
    #pragma unroll
    for (int j = 0; j < U; ++j) a[j] = bf2f(Sin[(size_t)e[j].x * 64 + lane]);
    #pragma unroll
    for (int j = 0; j < U; ++j) acc += __int_as_float(e[j].y) * a[j];
}

// ---- final layer fused: SpMM only at batch rows, accumulate f32 into out ----
__global__ void k_spmm_b(const unsigned short* __restrict__ Sin,
                         const void* __restrict__ users, const void* __restrict__ items,
                         const int* __restrict__ rowstart, const int2* __restrict__ edges,
                         float* __restrict__ out, const int* __restrict__ flags,
                         int B, int NU, int NI) {
    int tid = blockIdx.x * blockDim.x + threadIdx.x;
    int wid = tid >> 6, lane = threadIdx.x & 63;
    if (wid >= 2 * B) return;
    int wide = flags[4] > WTHR;
    int row;
    if (wid < B) row = clampi(idx_at(users, wid, wide), NU);
    else         row = NU + clampi(idx_at(items, wid - B, wide), NI);
    int start = __builtin_amdgcn_readfirstlane(rowstart[row]);
    int end   = __builtin_amdgcn_readfirstlane(rowstart[row + 1]);
    float acc = 0.f;
    int k = start;
    for (; k + 16 <= end; k += 16) spmm_batchB<16>(Sin, edges, k, lane, acc);
    if (k + 8 <= end) { spmm_batchB<8>(Sin, edges, k, lane, acc); k += 8; }
    if (k + 4 <= end) { spmm_batchB<4>(Sin, edges, k, lane, acc); k += 4; }
    if (k + 2 <= end) { spmm_batchB<2>(Sin, edges, k, lane, acc); k += 2; }
    if (k < end)      { spmm_batchB<1>(Sin, edges, k, lane, acc); }
    out[(size_t)wid * 64 + lane] += acc;
}

// ---- epilogue: add layer1(S1)+layer2(S0) batch rows, scale 1/4, scores ----
__global__ void epilogue(float* __restrict__ out,
                         const unsigned short* __restrict__ S0,
                         const unsigned short* __restrict__ S1,
                         const void* __restrict__ users, const void* __restrict__ items,
                         const int* __restrict__ flags, int B, int NU, int NI) {
    int tid = blockIdx.x * blockDim.x + threadIdx.x;
    int b = tid >> 6, d = tid & 63;
    if (b >= B) return;
    int wide = flags[4] > WTHR;
    long long urow = clampi(idx_at(users, b, wide), NU);
    long long irow = (long long)NU + clampi(idx_at(items, b, wide), NI);
    float u = (out[tid] + bf2f(S1[urow * 64 + d]) + bf2f(S0[urow * 64 + d])) * 0.25f;
    float i = (out[B * 64 + tid] + bf2f(S1[irow * 64 + d]) + bf2f(S0[irow * 64 + d])) * 0.25f;
    out[tid] = u;
    out[B * 64 + tid] = i;
    float p = u * i;
    #pragma unroll
    for (int off = 32; off > 0; off >>= 1) p += __shfl_down(p, off, 64);
    if (d == 0) out[2 * B * 64 + b] = p;
}

__global__ void diag_fill(float* __restrict__ out, int n, float marker) {
    int tid = blockIdx.x * blockDim.x + threadIdx.x;
    if (tid < n) out[tid] = marker;
}

extern "C" void kernel_launch(void* const* d_in, const int* in_sizes, int n_in,
                              void* d_out, int out_size, void* d_ws, size_t ws_size,
                              hipStream_t stream) {
    const void* ue    = d_in[0];
    const void* ie    = d_in[1];
    const void* esrc  = d_in[2];
    const void* edst  = d_in[3];
    const void* eval  = d_in[4];
    const void* users = d_in[5];
    const void* items = d_in[6];
    float* out = (float*)d_out;

    const int TPB = 256;
    if (n_in != 7) {
        diag_fill<<<(out_size + TPB - 1) / TPB, TPB, 0, stream>>>(out, out_size,
                                                                  3000.0f + 64.0f * n_in);
        return;
    }

    const int NU = in_sizes[0] / DIM;
    const int NI = in_sizes[1] / DIM;
    const int N  = NU + NI;
    const int E  = in_sizes[2];
    const int B  = in_sizes[5];
    const int K    = (N + BSZ - 1) >> SHIFT;
    const int NBLK = (E + CHUNK - 1) / CHUNK;

    const size_t sBytes   = (size_t)N * DIM * sizeof(unsigned short);
    const size_t tmpBytes = sBytes > (size_t)E * 8 ? sBytes : (size_t)E * 8;
    size_t off = 0;
    auto take = [&](size_t bytes) { size_t o = off; off += (bytes + 255) & ~255ull; return o; };
    char* base = (char*)d_ws;
    unsigned short* S0   = (unsigned short*)(base + take(sBytes));
    unsigned short* S1   = (unsigned short*)(base + take(tmpBytes));   // doubles as TMP
    int2*  edges   = (int2*)(base + take((size_t)E * 8));
    int*   flags   = (int*)(base + take(64));
    int*   btotal  = (int*)(base + take((KMAX + 1) * 4));
    int*   gcur    = (int*)(base + take((KMAX + 1) * 4));
    int*   bucketStart = (int*)(base + take((KMAX + 2) * 4));
    int*   rowstart    = (int*)(base + take((size_t)(N + 1) * 4));
    const size_t need = off;

    if (ws_size < need || K > KMAX) {
        diag_fill<<<(out_size + TPB - 1) / TPB, TPB, 0, stream>>>(out, out_size,
                                                                  1000.0f + (float)(ws_size >> 20));
        return;
    }

    const int N16 = N * 16, NU16 = NU * 16;
    const int nStage = (N16 + 2 * B * 64 + TPB - 1) / TPB;
    dim3 gInit(5 + (K + 1 + TPB - 1) / TPB);
    dim3 gPrep(nStage + NBLK);
    dim3 gBatch((2 * B * 64 + TPB - 1) / TPB);
    dim3 gSpmm(((size_t)N * 64 + TPB - 1) / TPB);
    dim3 gEpi((B * 64 + TPB - 1) / TPB);

    // 1: sniff + zero btotal (replaces memset + sniff_all)
    k_init<<<gInit, TPB, 0, stream>>>((const unsigned*)ue, (const unsigned*)ie,
                                      (const unsigned*)eval, (const unsigned*)esrc,
                                      (const unsigned*)users, flags, btotal, K);
    // 2: stage S0 + layer-0 gather || bucket count
    k_prep<<<gPrep, TPB, 0, stream>>>(ue, ie, users, items, edst, (ushort4*)S0, out,
                                      btotal, flags, NU16, N16, B, NU, NI, E, N, K,
                                      nStage);
    // 3-5: scan -> reserve+scatter -> in-bucket sort
    k_scanB<<<1, SBT, 0, stream>>>(btotal, bucketStart, gcur, rowstart, K, N);
    k_scat<<<NBLK, CTPB, 0, stream>>>(esrc, edst, eval, flags, gcur,
                                      (unsigned long long*)S1, E, N, K);
    k_p2sort<<<K, STPB, 0, stream>>>((const unsigned long long*)S1, bucketStart,
                                     edges, rowstart, N);

    // 6-8: layers 1,2 full SpMM; layer 3 batch-row SpMM
    k_spmm<<<gSpmm, TPB, 0, stream>>>(S0, S1, rowstart, edges, N);
    k_spmm<<<gSpmm, TPB, 0, stream>>>(S1, S0, rowstart, edges, N);
    k_spmm_b<<<gBatch, TPB, 0, stream>>>(S0, users, items, rowstart, edges, out, flags,
                                         B, NU, NI);
    // 9: epilogue folds layer1 (S1) + layer2 (S0) batch accumulation + scores
    epilogue<<<gEpi, TPB, 0, stream>>>(out, S0, S1, users, items, flags, B, NU, NI);
}

// Round 11
// 572.953 us; speedup vs baseline: 1.0501x; 1.0501x over previous
//
#include <hip/hip_runtime.h>
#include <hip/hip_bf16.h>

// LightGCN on MI355X — round 20.
// R19 post-mortem: dispatch-cut was NEUTRAL (+4us) -> launch overhead is NOT
// the cost; the ~350us non-spmm time is real execution in k_prep/k_scat/
// k_p2sort, all ~5-7x above BW floor -> latency/occupancy-bound (~9 waves/CU).
// Also R19 silently changed count's block size 512->256 (regression).
// R20: raise waves/CU WITHOUT changing geometry: p2sort 512->1024 thr
// (PER=1, 16 waves/block), scat 512->1024 thr (SPT=16, CHUNK unchanged ->
// run length unchanged), k_prep at 512 thr (restores count's 32-iter shape).
// Predict total 601.6 -> ~555-575; if <10us, sort is LDS-atomic/barrier-bound
// and ~600 is this decomposition's floor.

#define DIM   64
#define FTHR  2048   // float sniff: >FTHR of 4096 words look bf16-packed
#define WTHR  512    // wide sniff:  >WTHR of 1024 odd words are zero -> int64
#define SHIFT 10
#define BSZ   (1 << SHIFT)     // 1024 dst rows per bucket
#define KMAX  1023             // scanB (1024 thr) handles up to 1023 buckets
#define CHUNK 16384            // edges per count/scat block
#define PTPB  512              // k_prep threads per block
#define CTPB  1024             // scat threads per block
#define SPT   (CHUNK / CTPB)   // 16 edges per thread in scat
#define STPB  1024             // p2sort threads per block
#define SBT   1024             // scanB threads

__device__ __forceinline__ float bf2f(unsigned short u) {
    return __builtin_bit_cast(float, ((unsigned)u) << 16);
}
__device__ __forceinline__ unsigned short f2bf(float x) {
    return __builtin_bit_cast(unsigned short, __float2bfloat16(x));
}
__device__ __forceinline__ int idx_at(const void* a, long long i, int wide) {
    return wide ? (int)((const long long*)a)[i] : ((const int*)a)[i];
}
__device__ __forceinline__ int clampi(int v, int hi) {
    return v < 0 ? 0 : (v >= hi ? hi - 1 : v);
}

// ---- init: blocks 0-4 sniff -> flags[b] (plain store); blocks 5+ zero btotal
// flags: [0] ue float-kind [1] ie float-kind [2] eval float-kind
//        [3] edge idx wide [4] batch idx wide
__global__ void k_init(const unsigned* __restrict__ ue, const unsigned* __restrict__ ie,
                       const unsigned* __restrict__ eval, const unsigned* __restrict__ esrc,
                       const unsigned* __restrict__ users, int* __restrict__ flags,
                       int* __restrict__ btotal, int K) {
    int b = blockIdx.x, t = threadIdx.x;
    if (b < 5) {
        const unsigned* p = (b == 0) ? ue : (b == 1) ? ie : (b == 2) ? eval
                           : (b == 3) ? esrc : users;
        int cnt = 0;
        if (b < 3) {
            for (int i = t; i < 4096; i += 256) {
                unsigned e = (p[i] >> 7) & 0xffu;
                if (e >= 110u && e <= 135u) cnt++;
            }
        } else {
            for (int i = t; i < 1024; i += 256)
                if (p[2 * i + 1] == 0u) cnt++;
        }
        __shared__ int part[4];
        #pragma unroll
        for (int off = 32; off > 0; off >>= 1) cnt += __shfl_down(cnt, off, 64);
        if ((t & 63) == 0) part[t >> 6] = cnt;
        __syncthreads();
        if (t == 0) flags[b] = part[0] + part[1] + part[2] + part[3];
    } else {
        int i = (b - 5) * 256 + t;
        if (i <= K) btotal[i] = 0;
    }
}

// ---- prep: blocks [0,nStage) stage S0 + layer-0 gather; rest: bucket count
__global__ __launch_bounds__(PTPB) void k_prep(const void* __restrict__ ue,
                       const void* __restrict__ ie,
                       const void* __restrict__ users, const void* __restrict__ items,
                       const void* __restrict__ edst,
                       ushort4* __restrict__ S, float* __restrict__ out,
                       int* __restrict__ btotal, const int* __restrict__ flags,
                       int NU16, int N16, int B, int NU, int NI,
                       int E, int N, int K, int nStage) {
    if (blockIdx.x < nStage) {
        int tid = blockIdx.x * PTPB + threadIdx.x;
        if (tid < N16) {
            // stage: one ushort4 (4 bf16) per thread
            bool user = tid < NU16;
            const void* src = user ? ue : ie;
            int fl  = user ? flags[0] : flags[1];
            int idx = user ? tid : tid - NU16;
            ushort4 o;
            if (fl > FTHR) {
                o = ((const ushort4*)src)[idx];
            } else {
                float4 v = ((const float4*)src)[idx];
                o.x = f2bf(v.x); o.y = f2bf(v.y); o.z = f2bf(v.z); o.w = f2bf(v.w);
            }
            S[tid] = o;
        } else {
            // layer-0 gather: out[slot] = input emb (f32)
            int g = tid - N16;
            int r = g >> 6, d = g & 63;
            if (r >= 2 * B) return;
            int wide = flags[4] > WTHR;
            const void* src; long long row; int fl;
            if (r < B) { row = clampi(idx_at(users, r, wide), NU); src = ue; fl = flags[0]; }
            else       { row = clampi(idx_at(items, r - B, wide), NI); src = ie; fl = flags[1]; }
            float v;
            if (fl > FTHR) v = bf2f(((const unsigned short*)src)[row * 64 + d]);
            else           v = ((const float*)src)[row * 64 + d];
            out[g] = v;
        }
    } else {
        // count: per-block LDS hist -> global atomic bucket totals (32 iters)
        __shared__ int h[KMAX + 1];
        int t = threadIdx.x;
        for (int i = t; i < K; i += PTPB) h[i] = 0;
        __syncthreads();
        int wide = flags[3] > WTHR;
        int base = (blockIdx.x - nStage) * CHUNK;
        int lim = min(base + CHUNK, E);
        for (int i = base + t; i < lim; i += PTPB) {
            int d = clampi(idx_at(edst, i, wide), N);
            atomicAdd(&h[d >> SHIFT], 1);
        }
        __syncthreads();
        for (int i = t; i < K; i += PTPB)
            if (h[i]) atomicAdd(&btotal[i], h[i]);
    }
}

// ---- scanB: bucket starts + init global cursors (1 block, 1024 thr) ----
__global__ __launch_bounds__(SBT) void k_scanB(const int* __restrict__ btotal,
                        int* __restrict__ bucketStart, int* __restrict__ gcur,
                        int* __restrict__ rowstart, int K, int N) {
    __shared__ int sh[SBT];
    int t = threadIdx.x;
    int v = (t < K) ? btotal[t] : 0;
    sh[t] = v;
    for (int off = 1; off < SBT; off <<= 1) {
        __syncthreads();
        int y = (t >= off) ? sh[t - off] : 0;
        __syncthreads();
        sh[t] += y;
    }
    __syncthreads();
    if (t <= K) bucketStart[t] = sh[t] - v;   // exclusive (t=K: v=0 -> total)
    if (t < K)  gcur[t] = sh[t] - v;
    if (t == SBT - 1) rowstart[N] = sh[SBT - 1];  // total edge count
}

// ---- scat: reserve bucket ranges dynamically, LDS-cursor scatter ----
// 1024 thr (SPT=16); CHUNK unchanged -> per-bucket run length unchanged.
__global__ __launch_bounds__(CTPB) void k_scat(const void* __restrict__ esrc,
                       const void* __restrict__ edst,
                       const void* __restrict__ eval, const int* __restrict__ flags,
                       int* __restrict__ gcur, unsigned long long* __restrict__ TMP,
                       int E, int N, int K) {
    __shared__ int h[KMAX + 1];
    __shared__ int cur[KMAX + 1];
    int t = threadIdx.x;
    for (int i = t; i < K; i += CTPB) h[i] = 0;
    __syncthreads();
    int wide = flags[3] > WTHR;
    int evalbf = flags[2] > FTHR;
    int base = blockIdx.x * CHUNK;
    int lim = min(base + CHUNK, E);
    // pass A: chunk histogram; stash d in registers (static indexing)
    int dstash[SPT];
    #pragma unroll
    for (int j = 0; j < SPT; ++j) {
        int i = base + t + j * CTPB;
        int d = 0;
        if (i < lim) {
            d = clampi(idx_at(edst, i, wide), N);
            atomicAdd(&h[d >> SHIFT], 1);
        }
        dstash[j] = d;
    }
    __syncthreads();
    // reserve contiguous ranges in each touched bucket
    for (int i = t; i < K; i += CTPB)
        if (h[i]) cur[i] = atomicAdd(&gcur[i], h[i]);
    __syncthreads();
    // pass B: scatter via LDS cursors (runs of ~56 edges/bucket = 448B)
    #pragma unroll
    for (int j = 0; j < SPT; ++j) {
        int i = base + t + j * CTPB;
        if (i >= lim) continue;
        int d = dstash[j];
        int s = clampi(idx_at(esrc, i, wide), N);
        unsigned short vb = evalbf ? ((const unsigned short*)eval)[i]
                                   : f2bf(((const float*)eval)[i]);
        int b = d >> SHIFT;
        unsigned dl = (unsigned)(d & (BSZ - 1));
        int slot = atomicAdd(&cur[b], 1);
        unsigned long long p = (unsigned long long)(unsigned)s
                             | (((unsigned long long)((dl << 16) | vb)) << 32);
        TMP[slot] = p;
    }
}

// ---- sort pass 2: in-bucket counting sort + rowstart (1 block/bucket, 1024 thr)
__global__ __launch_bounds__(STPB) void k_p2sort(const unsigned long long* __restrict__ TMP,
                         const int* __restrict__ bucketStart,
                         int2* __restrict__ edges, int* __restrict__ rowstart,
                         int N) {
    __shared__ int hist[BSZ];
    __shared__ int wsum[STPB / 64];
    int b = blockIdx.x;
    int t = threadIdx.x;
    int span0 = bucketStart[b], span1 = bucketStart[b + 1];
    int rbase = b << SHIFT;
    int nrows = min(BSZ, N - rbase);
    for (int i = t; i < BSZ; i += STPB) hist[i] = 0;
    __syncthreads();
    for (int e = span0 + t; e < span1; e += STPB) {
        int dl = (int)((TMP[e] >> 48) & (BSZ - 1));
        atomicAdd(&hist[dl], 1);
    }
    __syncthreads();
    // block-wide exclusive prefix sum over BSZ entries, 1/thread
    const int PER = BSZ / STPB;   // 1
    int loc[PER];
    int s = 0;
    #pragma unroll
    for (int j = 0; j < PER; ++j) {
        int v = hist[t * PER + j];
        loc[j] = s;
        s += v;
    }
    int wid = t >> 6, lane = t & 63;
    int x = s;
    #pragma unroll
    for (int off = 1; off < 64; off <<= 1) {
        int y = __shfl_up(x, off, 64);
        if (lane >= off) x += y;
    }
    if (lane == 63) wsum[wid] = x;
    __syncthreads();
    int wbase = 0;
    #pragma unroll
    for (int w = 0; w < STPB / 64; ++w) wbase += (w < wid) ? wsum[w] : 0;
    int texcl = wbase + x - s;
    #pragma unroll
    for (int j = 0; j < PER; ++j) hist[t * PER + j] = texcl + loc[j];
    __syncthreads();
    // rowstart for this bucket's rows
    for (int r = t; r < nrows; r += STPB) rowstart[rbase + r] = span0 + hist[r];
    __syncthreads();
    // scatter to final sorted position (hist doubles as cursor)
    for (int e = span0 + t; e < span1; e += STPB) {
        unsigned long long p = TMP[e];
        int dl = (int)((p >> 48) & (BSZ - 1));
        unsigned vb = (unsigned)((p >> 32) & 0xffffu);
        int src = (int)(unsigned)p;
        int slot = span0 + atomicAdd(&hist[dl], 1);
        edges[slot] = make_int2(src, (int)(vb << 16));
    }
}

// ---- atomic-free SpMM body — k_spmm's private copy (R16 frozen form) ----
template <int U>
__device__ __forceinline__ void spmm_batchA(const unsigned short* __restrict__ Sin,
                                            const int2* __restrict__ edges,
                                            int k, int lane, float& acc) {
    int2 e[U];
    #pragma unroll
    for (int j = 0; j < U; ++j) e[j] = edges[k + j];
    float a[U];
    #pragma unroll
    for (int j = 0; j < U; ++j) a[j] = bf2f(Sin[(size_t)e[j].x * 64 + lane]);
    #pragma unroll
    for (int j = 0; j < U; ++j) acc += __int_as_float(e[j].y) * a[j];
}

// ---- full SpMM: one wave per dst row, lane = dim (FROZEN, do not touch) ----
__global__ void k_spmm(const unsigned short* __restrict__ Sin,
                       unsigned short* __restrict__ Sout,
                       const int* __restrict__ rowstart,
                       const int2* __restrict__ edges, int N) {
    int wid = (blockIdx.x * blockDim.x + threadIdx.x) >> 6;
    int lane = threadIdx.x & 63;
    if (wid >= N) return;
    int start = __builtin_amdgcn_readfirstlane(rowstart[wid]);
    int end   = __builtin_amdgcn_readfirstlane(rowstart[wid + 1]);
    float acc = 0.f;
    int k = start;
    for (; k + 16 <= end; k += 16) spmm_batchA<16>(Sin, edges, k, lane, acc);
    if (k + 8 <= end) { spmm_batchA<8>(Sin, edges, k, lane, acc); k += 8; }
    if (k + 4 <= end) { spmm_batchA<4>(Sin, edges, k, lane, acc); k += 4; }
    if (k + 2 <= end) { spmm_batchA<2>(Sin, edges, k, lane, acc); k += 2; }
    if (k < end)      { spmm_batchA<1>(Sin, edges, k, lane, acc); }
    __builtin_nontemporal_store(f2bf(acc), &Sout[(size_t)wid * 64 + lane]);
}

// ---- k_spmm_b's private copy of the body (codegen isolation) ----
template <int U>
__device__ __forceinline__ void spmm_batchB(const unsigned short* __restrict__ Sin,
                                            const int2* __restrict__ edges,
                                            int k, int lane, float& acc) {
    int2 e[U];
    #pragma unroll
    for (int j = 0; j < U; ++j) e[j] = edges[k + j];
    float a[U];
    #pragma unroll
    for (int j = 0; j < U; ++j) a[j] = bf2f(Sin[(size_t)e[j].x * 64 + lane]);
    #pragma unroll
    for (int j = 0; j < U; ++j) acc += __int_as_float(e[j].y) * a[j];
}

// ---- final layer fused: SpMM only at batch rows, accumulate f32 into out ----
__global__ void k_spmm_b(const unsigned short* __restrict__ Sin,
                         const void* __restrict__ users, const void* __restrict__ items,
                         const int* __restrict__ rowstart, const int2* __restrict__ edges,
                         float* __restrict__ out, const int* __restrict__ flags,
                         int B, int NU, int NI) {
    int tid = blockIdx.x * blockDim.x + threadIdx.x;
    int wid = tid >> 6, lane = threadIdx.x & 63;
    if (wid >= 2 * B) return;
    int wide = flags[4] > WTHR;
    int row;
    if (wid < B) row = clampi(idx_at(users, wid, wide), NU);
    else         row = NU + clampi(idx_at(items, wid - B, wide), NI);
    int start = __builtin_amdgcn_readfirstlane(rowstart[row]);
    int end   = __builtin_amdgcn_readfirstlane(rowstart[row + 1]);
    float acc = 0.f;
    int k = start;
    for (; k + 16 <= end; k += 16) spmm_batchB<16>(Sin, edges, k, lane, acc);
    if (k + 8 <= end) { spmm_batchB<8>(Sin, edges, k, lane, acc); k += 8; }
    if (k + 4 <= end) { spmm_batchB<4>(Sin, edges, k, lane, acc); k += 4; }
    if (k + 2 <= end) { spmm_batchB<2>(Sin, edges, k, lane, acc); k += 2; }
    if (k < end)      { spmm_batchB<1>(Sin, edges, k, lane, acc); }
    out[(size_t)wid * 64 + lane] += acc;
}

// ---- epilogue: add layer1(S1)+layer2(S0) batch rows, scale 1/4, scores ----
__global__ void epilogue(float* __restrict__ out,
                         const unsigned short* __restrict__ S0,
                         const unsigned short* __restrict__ S1,
                         const void* __restrict__ users, const void* __restrict__ items,
                         const int* __restrict__ flags, int B, int NU, int NI) {
    int tid = blockIdx.x * blockDim.x + threadIdx.x;
    int b = tid >> 6, d = tid & 63;
    if (b >= B) return;
    int wide = flags[4] > WTHR;
    long long urow = clampi(idx_at(users, b, wide), NU);
    long long irow = (long long)NU + clampi(idx_at(items, b, wide), NI);
    float u = (out[tid] + bf2f(S1[urow * 64 + d]) + bf2f(S0[urow * 64 + d])) * 0.25f;
    float i = (out[B * 64 + tid] + bf2f(S1[irow * 64 + d]) + bf2f(S0[irow * 64 + d])) * 0.25f;
    out[tid] = u;
    out[B * 64 + tid] = i;
    float p = u * i;
    #pragma unroll
    for (int off = 32; off > 0; off >>= 1) p += __shfl_down(p, off, 64);
    if (d == 0) out[2 * B * 64 + b] = p;
}

__global__ void diag_fill(float* __restrict__ out, int n, float marker) {
    int tid = blockIdx.x * blockDim.x + threadIdx.x;
    if (tid < n) out[tid] = marker;
}

extern "C" void kernel_launch(void* const* d_in, const int* in_sizes, int n_in,
                              void* d_out, int out_size, void* d_ws, size_t ws_size,
                              hipStream_t stream) {
    const void* ue    = d_in[0];
    const void* ie    = d_in[1];
    const void* esrc  = d_in[2];
    const void* edst  = d_in[3];
    const void* eval  = d_in[4];
    const void* users = d_in[5];
    const void* items = d_in[6];
    float* out = (float*)d_out;

    const int TPB = 256;
    if (n_in != 7) {
        diag_fill<<<(out_size + TPB - 1) / TPB, TPB, 0, stream>>>(out, out_size,
                                                                  3000.0f + 64.0f * n_in);
        return;
    }

    const int NU = in_sizes[0] / DIM;
    const int NI = in_sizes[1] / DIM;
    const int N  = NU + NI;
    const int E  = in_sizes[2];
    const int B  = in_sizes[5];
    const int K    = (N + BSZ - 1) >> SHIFT;
    const int NBLK = (E + CHUNK - 1) / CHUNK;

    const size_t sBytes   = (size_t)N * DIM * sizeof(unsigned short);
    const size_t tmpBytes = sBytes > (size_t)E * 8 ? sBytes : (size_t)E * 8;
    size_t off = 0;
    auto take = [&](size_t bytes) { size_t o = off; off += (bytes + 255) & ~255ull; return o; };
    char* base = (char*)d_ws;
    unsigned short* S0   = (unsigned short*)(base + take(sBytes));
    unsigned short* S1   = (unsigned short*)(base + take(tmpBytes));   // doubles as TMP
    int2*  edges   = (int2*)(base + take((size_t)E * 8));
    int*   flags   = (int*)(base + take(64));
    int*   btotal  = (int*)(base + take((KMAX + 1) * 4));
    int*   gcur    = (int*)(base + take((KMAX + 1) * 4));
    int*   bucketStart = (int*)(base + take((KMAX + 2) * 4));
    int*   rowstart    = (int*)(base + take((size_t)(N + 1) * 4));
    const size_t need = off;

    if (ws_size < need || K > KMAX) {
        diag_fill<<<(out_size + TPB - 1) / TPB, TPB, 0, stream>>>(out, out_size,
                                                                  1000.0f + (float)(ws_size >> 20));
        return;
    }

    const int N16 = N * 16, NU16 = NU * 16;
    const int nStage = (N16 + 2 * B * 64 + PTPB - 1) / PTPB;
    dim3 gInit(5 + (K + 1 + TPB - 1) / TPB);
    dim3 gPrep(nStage + NBLK);
    dim3 gBatch((2 * B * 64 + TPB - 1) / TPB);
    dim3 gSpmm(((size_t)N * 64 + TPB - 1) / TPB);
    dim3 gEpi((B * 64 + TPB - 1) / TPB);

    // 1: sniff + zero btotal
    k_init<<<gInit, TPB, 0, stream>>>((const unsigned*)ue, (const unsigned*)ie,
                                      (const unsigned*)eval, (const unsigned*)esrc,
                                      (const unsigned*)users, flags, btotal, K);
    // 2: stage S0 + layer-0 gather || bucket count (512 thr)
    k_prep<<<gPrep, PTPB, 0, stream>>>(ue, ie, users, items, edst, (ushort4*)S0, out,
                                       btotal, flags, NU16, N16, B, NU, NI, E, N, K,
                                       nStage);
    // 3-5: scan -> reserve+scatter (1024 thr) -> in-bucket sort (1024 thr)
    k_scanB<<<1, SBT, 0, stream>>>(btotal, bucketStart, gcur, rowstart, K, N);
    k_scat<<<NBLK, CTPB, 0, stream>>>(esrc, edst, eval, flags, gcur,
                                      (unsigned long long*)S1, E, N, K);
    k_p2sort<<<K, STPB, 0, stream>>>((const unsigned long long*)S1, bucketStart,
                                     edges, rowstart, N);

    // 6-8: layers 1,2 full SpMM; layer 3 batch-row SpMM
    k_spmm<<<gSpmm, TPB, 0, stream>>>(S0, S1, rowstart, edges, N);
    k_spmm<<<gSpmm, TPB, 0, stream>>>(S1, S0, rowstart, edges, N);
    k_spmm_b<<<gBatch, TPB, 0, stream>>>(S0, users, items, rowstart, edges, out, flags,
                                         B, NU, NI);
    // 9: epilogue folds layer1 (S1) + layer2 (S0) batch accumulation + scores
    epilogue<<<gEpi, TPB, 0, stream>>>(out, S0, S1, users, items, flags, B, NU, NI);
}

// Round 12
// 570.572 us; speedup vs baseline: 1.0545x; 1.0042x over previous
//
#include <hip/hip_runtime.h>
#include <hip/hip_bf16.h>

// LightGCN on MI355X — round 21.
// R20: WIN (573.0, best). Sort occupancy lever confirmed (+28.7us).
// R21: same lever, next notch. p2sort still ~18 waves/CU (294 blocks x 16
// waves). SHIFT 10->9 with CHUNK UNCHANGED (16384): K=587 blocks -> full
// ~32 waves/CU, bucket span halves. Cost: scat run length 56->28 edges
// (224B ~ 2 lines, write amp ~1.4x, +2-3us) — NOT R15's 7-edge disaster.
// p2sort prefix-scan restructured for STPB=1024 > BSZ=512 (t<512 own one
// entry; barriers uniform). spmm FROZEN. Predict 573 -> ~545-558; if <8us
// or regress -> revert SHIFT 10, decomposition at floor.

#define DIM   64
#define FTHR  2048   // float sniff: >FTHR of 4096 words look bf16-packed
#define WTHR  512    // wide sniff:  >WTHR of 1024 odd words are zero -> int64
#define SHIFT 9
#define BSZ   (1 << SHIFT)     // 512 dst rows per bucket
#define KMAX  1023             // scanB (1024 thr) handles up to 1023 buckets
#define CHUNK 16384            // edges per count/scat block (run length 28)
#define PTPB  512              // k_prep threads per block
#define CTPB  1024             // scat threads per block
#define SPT   (CHUNK / CTPB)   // 16 edges per thread in scat
#define STPB  1024             // p2sort threads per block
#define SBT   1024             // scanB threads

__device__ __forceinline__ float bf2f(unsigned short u) {
    return __builtin_bit_cast(float, ((unsigned)u) << 16);
}
__device__ __forceinline__ unsigned short f2bf(float x) {
    return __builtin_bit_cast(unsigned short, __float2bfloat16(x));
}
__device__ __forceinline__ int idx_at(const void* a, long long i, int wide) {
    return wide ? (int)((const long long*)a)[i] : ((const int*)a)[i];
}
__device__ __forceinline__ int clampi(int v, int hi) {
    return v < 0 ? 0 : (v >= hi ? hi - 1 : v);
}

// ---- init: blocks 0-4 sniff -> flags[b] (plain store); blocks 5+ zero btotal
// flags: [0] ue float-kind [1] ie float-kind [2] eval float-kind
//        [3] edge idx wide [4] batch idx wide
__global__ void k_init(const unsigned* __restrict__ ue, const unsigned* __restrict__ ie,
                       const unsigned* __restrict__ eval, const unsigned* __restrict__ esrc,
                       const unsigned* __restrict__ users, int* __restrict__ flags,
                       int* __restrict__ btotal, int K) {
    int b = blockIdx.x, t = threadIdx.x;
    if (b < 5) {
        const unsigned* p = (b == 0) ? ue : (b == 1) ? ie : (b == 2) ? eval
                           : (b == 3) ? esrc : users;
        int cnt = 0;
        if (b < 3) {
            for (int i = t; i < 4096; i += 256) {
                unsigned e = (p[i] >> 7) & 0xffu;
                if (e >= 110u && e <= 135u) cnt++;
            }
        } else {
            for (int i = t; i < 1024; i += 256)
                if (p[2 * i + 1] == 0u) cnt++;
        }
        __shared__ int part[4];
        #pragma unroll
        for (int off = 32; off > 0; off >>= 1) cnt += __shfl_down(cnt, off, 64);
        if ((t & 63) == 0) part[t >> 6] = cnt;
        __syncthreads();
        if (t == 0) flags[b] = part[0] + part[1] + part[2] + part[3];
    } else {
        int i = (b - 5) * 256 + t;
        if (i <= K) btotal[i] = 0;
    }
}

// ---- prep: blocks [0,nStage) stage S0 + layer-0 gather; rest: bucket count
__global__ __launch_bounds__(PTPB) void k_prep(const void* __restrict__ ue,
                       const void* __restrict__ ie,
                       const void* __restrict__ users, const void* __restrict__ items,
                       const void* __restrict__ edst,
                       ushort4* __restrict__ S, float* __restrict__ out,
                       int* __restrict__ btotal, const int* __restrict__ flags,
                       int NU16, int N16, int B, int NU, int NI,
                       int E, int N, int K, int nStage) {
    if (blockIdx.x < nStage) {
        int tid = blockIdx.x * PTPB + threadIdx.x;
        if (tid < N16) {
            // stage: one ushort4 (4 bf16) per thread
            bool user = tid < NU16;
            const void* src = user ? ue : ie;
            int fl  = user ? flags[0] : flags[1];
            int idx = user ? tid : tid - NU16;
            ushort4 o;
            if (fl > FTHR) {
                o = ((const ushort4*)src)[idx];
            } else {
                float4 v = ((const float4*)src)[idx];
                o.x = f2bf(v.x); o.y = f2bf(v.y); o.z = f2bf(v.z); o.w = f2bf(v.w);
            }
            S[tid] = o;
        } else {
            // layer-0 gather: out[slot] = input emb (f32)
            int g = tid - N16;
            int r = g >> 6, d = g & 63;
            if (r >= 2 * B) return;
            int wide = flags[4] > WTHR;
            const void* src; long long row; int fl;
            if (r < B) { row = clampi(idx_at(users, r, wide), NU); src = ue; fl = flags[0]; }
            else       { row = clampi(idx_at(items, r - B, wide), NI); src = ie; fl = flags[1]; }
            float v;
            if (fl > FTHR) v = bf2f(((const unsigned short*)src)[row * 64 + d]);
            else           v = ((const float*)src)[row * 64 + d];
            out[g] = v;
        }
    } else {
        // count: per-block LDS hist -> global atomic bucket totals (32 iters)
        __shared__ int h[KMAX + 1];
        int t = threadIdx.x;
        for (int i = t; i < K; i += PTPB) h[i] = 0;
        __syncthreads();
        int wide = flags[3] > WTHR;
        int base = (blockIdx.x - nStage) * CHUNK;
        int lim = min(base + CHUNK, E);
        for (int i = base + t; i < lim; i += PTPB) {
            int d = clampi(idx_at(edst, i, wide), N);
            atomicAdd(&h[d >> SHIFT], 1);
        }
        __syncthreads();
        for (int i = t; i < K; i += PTPB)
            if (h[i]) atomicAdd(&btotal[i], h[i]);
    }
}

// ---- scanB: bucket starts + init global cursors (1 block, 1024 thr) ----
__global__ __launch_bounds__(SBT) void k_scanB(const int* __restrict__ btotal,
                        int* __restrict__ bucketStart, int* __restrict__ gcur,
                        int* __restrict__ rowstart, int K, int N) {
    __shared__ int sh[SBT];
    int t = threadIdx.x;
    int v = (t < K) ? btotal[t] : 0;
    sh[t] = v;
    for (int off = 1; off < SBT; off <<= 1) {
        __syncthreads();
        int y = (t >= off) ? sh[t - off] : 0;
        __syncthreads();
        sh[t] += y;
    }
    __syncthreads();
    if (t <= K) bucketStart[t] = sh[t] - v;   // exclusive (t=K: v=0 -> total)
    if (t < K)  gcur[t] = sh[t] - v;
    if (t == SBT - 1) rowstart[N] = sh[SBT - 1];  // total edge count
}

// ---- scat: reserve bucket ranges dynamically, LDS-cursor scatter ----
// 1024 thr (SPT=16); CHUNK 16384, K=587 -> runs of ~28 edges = 224B.
__global__ __launch_bounds__(CTPB) void k_scat(const void* __restrict__ esrc,
                       const void* __restrict__ edst,
                       const void* __restrict__ eval, const int* __restrict__ flags,
                       int* __restrict__ gcur, unsigned long long* __restrict__ TMP,
                       int E, int N, int K) {
    __shared__ int h[KMAX + 1];
    __shared__ int cur[KMAX + 1];
    int t = threadIdx.x;
    for (int i = t; i < K; i += CTPB) h[i] = 0;
    __syncthreads();
    int wide = flags[3] > WTHR;
    int evalbf = flags[2] > FTHR;
    int base = blockIdx.x * CHUNK;
    int lim = min(base + CHUNK, E);
    // pass A: chunk histogram; stash d in registers (static indexing)
    int dstash[SPT];
    #pragma unroll
    for (int j = 0; j < SPT; ++j) {
        int i = base + t + j * CTPB;
        int d = 0;
        if (i < lim) {
            d = clampi(idx_at(edst, i, wide), N);
            atomicAdd(&h[d >> SHIFT], 1);
        }
        dstash[j] = d;
    }
    __syncthreads();
    // reserve contiguous ranges in each touched bucket
    for (int i = t; i < K; i += CTPB)
        if (h[i]) cur[i] = atomicAdd(&gcur[i], h[i]);
    __syncthreads();
    // pass B: scatter via LDS cursors
    #pragma unroll
    for (int j = 0; j < SPT; ++j) {
        int i = base + t + j * CTPB;
        if (i >= lim) continue;
        int d = dstash[j];
        int s = clampi(idx_at(esrc, i, wide), N);
        unsigned short vb = evalbf ? ((const unsigned short*)eval)[i]
                                   : f2bf(((const float*)eval)[i]);
        int b = d >> SHIFT;
        unsigned dl = (unsigned)(d & (BSZ - 1));
        int slot = atomicAdd(&cur[b], 1);
        unsigned long long p = (unsigned long long)(unsigned)s
                             | (((unsigned long long)((dl << 16) | vb)) << 32);
        TMP[slot] = p;
    }
}

// ---- sort pass 2: in-bucket counting sort + rowstart (1 block/bucket, 1024 thr)
// BSZ=512 < STPB=1024: threads t<512 own one hist entry in the scan.
__global__ __launch_bounds__(STPB) void k_p2sort(const unsigned long long* __restrict__ TMP,
                         const int* __restrict__ bucketStart,
                         int2* __restrict__ edges, int* __restrict__ rowstart,
                         int N) {
    __shared__ int hist[BSZ];
    __shared__ int wsum[STPB / 64];
    int b = blockIdx.x;
    int t = threadIdx.x;
    int span0 = bucketStart[b], span1 = bucketStart[b + 1];
    int rbase = b << SHIFT;
    int nrows = min(BSZ, N - rbase);
    for (int i = t; i < BSZ; i += STPB) hist[i] = 0;
    __syncthreads();
    for (int e = span0 + t; e < span1; e += STPB) {
        int dl = (int)((TMP[e] >> 48) & (BSZ - 1));
        atomicAdd(&hist[dl], 1);
    }
    __syncthreads();
    // block-wide exclusive prefix sum over BSZ=512 entries; t<512 participate,
    // all threads hit barriers uniformly.
    int wid = t >> 6, lane = t & 63;
    int v = (t < BSZ) ? hist[t] : 0;
    int x = v;
    #pragma unroll
    for (int off = 1; off < 64; off <<= 1) {
        int y = __shfl_up(x, off, 64);
        if (lane >= off) x += y;
    }
    if (lane == 63) wsum[wid] = x;
    __syncthreads();
    int wbase = 0;
    #pragma unroll
    for (int w = 0; w < STPB / 64; ++w) wbase += (w < wid) ? wsum[w] : 0;
    int texcl = wbase + x - v;     // exclusive prefix for entry t (t<BSZ)
    __syncthreads();
    if (t < BSZ) hist[t] = texcl;
    __syncthreads();
    // rowstart for this bucket's rows
    for (int r = t; r < nrows; r += STPB) rowstart[rbase + r] = span0 + hist[r];
    __syncthreads();
    // scatter to final sorted position (hist doubles as cursor)
    for (int e = span0 + t; e < span1; e += STPB) {
        unsigned long long p = TMP[e];
        int dl = (int)((p >> 48) & (BSZ - 1));
        unsigned vb = (unsigned)((p >> 32) & 0xffffu);
        int src = (int)(unsigned)p;
        int slot = span0 + atomicAdd(&hist[dl], 1);
        edges[slot] = make_int2(src, (int)(vb << 16));
    }
}

// ---- atomic-free SpMM body — k_spmm's private copy (R16 frozen form) ----
template <int U>
__device__ __forceinline__ void spmm_batchA(const unsigned short* __restrict__ Sin,
                                            const int2* __restrict__ edges,
                                            int k, int lane, float& acc) {
    int2 e[U];
    #pragma unroll
    for (int j = 0; j < U; ++j) e[j] = edges[k + j];
    float a[U];
    #pragma unroll
    for (int j = 0; j < U; ++j) a[j] = bf2f(Sin[(size_t)e[j].x * 64 + lane]);
    #pragma unroll
    for (int j = 0; j < U; ++j) acc += __int_as_float(e[j].y) * a[j];
}

// ---- full SpMM: one wave per dst row, lane = dim (FROZEN, do not touch) ----
__global__ void k_spmm(const unsigned short* __restrict__ Sin,
                       unsigned short* __restrict__ Sout,
                       const int* __restrict__ rowstart,
                       const int2* __restrict__ edges, int N) {
    int wid = (blockIdx.x * blockDim.x + threadIdx.x) >> 6;
    int lane = threadIdx.x & 63;
    if (wid >= N) return;
    int start = __builtin_amdgcn_readfirstlane(rowstart[wid]);
    int end   = __builtin_amdgcn_readfirstlane(rowstart[wid + 1]);
    float acc = 0.f;
    int k = start;
    for (; k + 16 <= end; k += 16) spmm_batchA<16>(Sin, edges, k, lane, acc);
    if (k + 8 <= end) { spmm_batchA<8>(Sin, edges, k, lane, acc); k += 8; }
    if (k + 4 <= end) { spmm_batchA<4>(Sin, edges, k, lane, acc); k += 4; }
    if (k + 2 <= end) { spmm_batchA<2>(Sin, edges, k, lane, acc); k += 2; }
    if (k < end)      { spmm_batchA<1>(Sin, edges, k, lane, acc); }
    __builtin_nontemporal_store(f2bf(acc), &Sout[(size_t)wid * 64 + lane]);
}

// ---- k_spmm_b's private copy of the body (codegen isolation) ----
template <int U>
__device__ __forceinline__ void spmm_batchB(const unsigned short* __restrict__ Sin,
                                            const int2* __restrict__ edges,
                                            int k, int lane, float& acc) {
    int2 e[U];
    #pragma unroll
    for (int j = 0; j < U; ++j) e[j] = edges[k + j];
    float a[U];
    #pragma unroll
    for (int j = 0; j < U; ++j) a[j] = bf2f(Sin[(size_t)e[j].x * 64 + lane]);
    #pragma unroll
    for (int j = 0; j < U; ++j) acc += __int_as_float(e[j].y) * a[j];
}

// ---- final layer fused: SpMM only at batch rows, accumulate f32 into out ----
__global__ void k_spmm_b(const unsigned short* __restrict__ Sin,
                         const void* __restrict__ users, const void* __restrict__ items,
                         const int* __restrict__ rowstart, const int2* __restrict__ edges,
                         float* __restrict__ out, const int* __restrict__ flags,
                         int B, int NU, int NI) {
    int tid = blockIdx.x * blockDim.x + threadIdx.x;
    int wid = tid >> 6, lane = threadIdx.x & 63;
    if (wid >= 2 * B) return;
    int wide = flags[4] > WTHR;
    int row;
    if (wid < B) row = clampi(idx_at(users, wid, wide), NU);
    else         row = NU + clampi(idx_at(items, wid - B, wide), NI);
    int start = __builtin_amdgcn_readfirstlane(rowstart[row]);
    int end   = __builtin_amdgcn_readfirstlane(rowstart[row + 1]);
    float acc = 0.f;
    int k = start;
    for (; k + 16 <= end; k += 16) spmm_batchB<16>(Sin, edges, k, lane, acc);
    if (k + 8 <= end) { spmm_batchB<8>(Sin, edges, k, lane, acc); k += 8; }
    if (k + 4 <= end) { spmm_batchB<4>(Sin, edges, k, lane, acc); k += 4; }
    if (k + 2 <= end) { spmm_batchB<2>(Sin, edges, k, lane, acc); k += 2; }
    if (k < end)      { spmm_batchB<1>(Sin, edges, k, lane, acc); }
    out[(size_t)wid * 64 + lane] += acc;
}

// ---- epilogue: add layer1(S1)+layer2(S0) batch rows, scale 1/4, scores ----
__global__ void epilogue(float* __restrict__ out,
                         const unsigned short* __restrict__ S0,
                         const unsigned short* __restrict__ S1,
                         const void* __restrict__ users, const void* __restrict__ items,
                         const int* __restrict__ flags, int B, int NU, int NI) {
    int tid = blockIdx.x * blockDim.x + threadIdx.x;
    int b = tid >> 6, d = tid & 63;
    if (b >= B) return;
    int wide = flags[4] > WTHR;
    long long urow = clampi(idx_at(users, b, wide), NU);
    long long irow = (long long)NU + clampi(idx_at(items, b, wide), NI);
    float u = (out[tid] + bf2f(S1[urow * 64 + d]) + bf2f(S0[urow * 64 + d])) * 0.25f;
    float i = (out[B * 64 + tid] + bf2f(S1[irow * 64 + d]) + bf2f(S0[irow * 64 + d])) * 0.25f;
    out[tid] = u;
    out[B * 64 + tid] = i;
    float p = u * i;
    #pragma unroll
    for (int off = 32; off > 0; off >>= 1) p += __shfl_down(p, off, 64);
    if (d == 0) out[2 * B * 64 + b] = p;
}

__global__ void diag_fill(float* __restrict__ out, int n, float marker) {
    int tid = blockIdx.x * blockDim.x + threadIdx.x;
    if (tid < n) out[tid] = marker;
}

extern "C" void kernel_launch(void* const* d_in, const int* in_sizes, int n_in,
                              void* d_out, int out_size, void* d_ws, size_t ws_size,
                              hipStream_t stream) {
    const void* ue    = d_in[0];
    const void* ie    = d_in[1];
    const void* esrc  = d_in[2];
    const void* edst  = d_in[3];
    const void* eval  = d_in[4];
    const void* users = d_in[5];
    const void* items = d_in[6];
    float* out = (float*)d_out;

    const int TPB = 256;
    if (n_in != 7) {
        diag_fill<<<(out_size + TPB - 1) / TPB, TPB, 0, stream>>>(out, out_size,
                                                                  3000.0f + 64.0f * n_in);
        return;
    }

    const int NU = in_sizes[0] / DIM;
    const int NI = in_sizes[1] / DIM;
    const int N  = NU + NI;
    const int E  = in_sizes[2];
    const int B  = in_sizes[5];
    const int K    = (N + BSZ - 1) >> SHIFT;
    const int NBLK = (E + CHUNK - 1) / CHUNK;

    const size_t sBytes   = (size_t)N * DIM * sizeof(unsigned short);
    const size_t tmpBytes = sBytes > (size_t)E * 8 ? sBytes : (size_t)E * 8;
    size_t off = 0;
    auto take = [&](size_t bytes) { size_t o = off; off += (bytes + 255) & ~255ull; return o; };
    char* base = (char*)d_ws;
    unsigned short* S0   = (unsigned short*)(base + take(sBytes));
    unsigned short* S1   = (unsigned short*)(base + take(tmpBytes));   // doubles as TMP
    int2*  edges   = (int2*)(base + take((size_t)E * 8));
    int*   flags   = (int*)(base + take(64));
    int*   btotal  = (int*)(base + take((KMAX + 1) * 4));
    int*   gcur    = (int*)(base + take((KMAX + 1) * 4));
    int*   bucketStart = (int*)(base + take((KMAX + 2) * 4));
    int*   rowstart    = (int*)(base + take((size_t)(N + 1) * 4));
    const size_t need = off;

    if (ws_size < need || K > KMAX) {
        diag_fill<<<(out_size + TPB - 1) / TPB, TPB, 0, stream>>>(out, out_size,
                                                                  1000.0f + (float)(ws_size >> 20));
        return;
    }

    const int N16 = N * 16, NU16 = NU * 16;
    const int nStage = (N16 + 2 * B * 64 + PTPB - 1) / PTPB;
    dim3 gInit(5 + (K + 1 + TPB - 1) / TPB);
    dim3 gPrep(nStage + NBLK);
    dim3 gBatch((2 * B * 64 + TPB - 1) / TPB);
    dim3 gSpmm(((size_t)N * 64 + TPB - 1) / TPB);
    dim3 gEpi((B * 64 + TPB - 1) / TPB);

    // 1: sniff + zero btotal
    k_init<<<gInit, TPB, 0, stream>>>((const unsigned*)ue, (const unsigned*)ie,
                                      (const unsigned*)eval, (const unsigned*)esrc,
                                      (const unsigned*)users, flags, btotal, K);
    // 2: stage S0 + layer-0 gather || bucket count (512 thr)
    k_prep<<<gPrep, PTPB, 0, stream>>>(ue, ie, users, items, edst, (ushort4*)S0, out,
                                       btotal, flags, NU16, N16, B, NU, NI, E, N, K,
                                       nStage);
    // 3-5: scan -> reserve+scatter (1024 thr) -> in-bucket sort (1024 thr, K=587)
    k_scanB<<<1, SBT, 0, stream>>>(btotal, bucketStart, gcur, rowstart, K, N);
    k_scat<<<NBLK, CTPB, 0, stream>>>(esrc, edst, eval, flags, gcur,
                                      (unsigned long long*)S1, E, N, K);
    k_p2sort<<<K, STPB, 0, stream>>>((const unsigned long long*)S1, bucketStart,
                                     edges, rowstart, N);

    // 6-8: layers 1,2 full SpMM; layer 3 batch-row SpMM
    k_spmm<<<gSpmm, TPB, 0, stream>>>(S0, S1, rowstart, edges, N);
    k_spmm<<<gSpmm, TPB, 0, stream>>>(S1, S0, rowstart, edges, N);
    k_spmm_b<<<gBatch, TPB, 0, stream>>>(S0, users, items, rowstart, edges, out, flags,
                                         B, NU, NI);
    // 9: epilogue folds layer1 (S1) + layer2 (S0) batch accumulation + scores
    epilogue<<<gEpi, TPB, 0, stream>>>(out, S0, S1, users, items, flags, B, NU, NI);
}

// Round 14
// 566.857 us; speedup vs baseline: 1.0614x; 1.0066x over previous
//
#include <hip/hip_runtime.h>
#include <hip/hip_bf16.h>

// LightGCN on MI355X — round 23 (= R22 resubmit; R22 bench was an infra
// failure, "container failed twice", no kernel signal — same as R13/R14).
// R21 post-mortem: p2sort occupancy gain (+) was offset by k_scat regression:
// top dispatch 111.2us, WRITE 106MB = 2.76x amp from 28-edge (224B) runs.
// Amp-vs-runlength measured: 7-edge->3.7x, 28->2.76x, 56->~1.9x (R16).
// R22/R23: keep SHIFT 9 / K=587 p2sort (occupancy win), DECOUPLE chunks:
// scat SCHUNK=32768 (restores 56-edge runs; SPT=32 static stash, VGPR~50),
// count stays 16384 (streaming occupancy). scat is RMW-bound (VALU 2.7%),
// not occupancy-bound -> 147 blocks is fine (same total waves as R16).
// Predict scat WRITE 106->~70MB, dur 111->~85-90; total 570.6 -> ~545-555.
// If scat >=105 still: amp is cross-XCD interleave -> revert to R20 geometry.

#define DIM    64
#define FTHR   2048  // float sniff: >FTHR of 4096 words look bf16-packed
#define WTHR   512   // wide sniff:  >WTHR of 1024 odd words are zero -> int64
#define SHIFT  9
#define BSZ    (1 << SHIFT)    // 512 dst rows per bucket
#define KMAX   1023            // scanB (1024 thr) handles up to 1023 buckets
#define CCHUNK 16384           // edges per count block
#define SCHUNK 32768           // edges per scat block (runs of ~56 = 448B)
#define PTPB   512             // k_prep threads per block
#define CTPB   1024            // scat threads per block
#define SPT    (SCHUNK / CTPB) // 32 edges per thread in scat
#define STPB   1024            // p2sort threads per block
#define SBT    1024            // scanB threads

__device__ __forceinline__ float bf2f(unsigned short u) {
    return __builtin_bit_cast(float, ((unsigned)u) << 16);
}
__device__ __forceinline__ unsigned short f2bf(float x) {
    return __builtin_bit_cast(unsigned short, __float2bfloat16(x));
}
__device__ __forceinline__ int idx_at(const void* a, long long i, int wide) {
    return wide ? (int)((const long long*)a)[i] : ((const int*)a)[i];
}
__device__ __forceinline__ int clampi(int v, int hi) {
    return v < 0 ? 0 : (v >= hi ? hi - 1 : v);
}

// ---- init: blocks 0-4 sniff -> flags[b] (plain store); blocks 5+ zero btotal
// flags: [0] ue float-kind [1] ie float-kind [2] eval float-kind
//        [3] edge idx wide [4] batch idx wide
__global__ void k_init(const unsigned* __restrict__ ue, const unsigned* __restrict__ ie,
                       const unsigned* __restrict__ eval, const unsigned* __restrict__ esrc,
                       const unsigned* __restrict__ users, int* __restrict__ flags,
                       int* __restrict__ btotal, int K) {
    int b = blockIdx.x, t = threadIdx.x;
    if (b < 5) {
        const unsigned* p = (b == 0) ? ue : (b == 1) ? ie : (b == 2) ? eval
                           : (b == 3) ? esrc : users;
        int cnt = 0;
        if (b < 3) {
            for (int i = t; i < 4096; i += 256) {
                unsigned e = (p[i] >> 7) & 0xffu;
                if (e >= 110u && e <= 135u) cnt++;
            }
        } else {
            for (int i = t; i < 1024; i += 256)
                if (p[2 * i + 1] == 0u) cnt++;
        }
        __shared__ int part[4];
        #pragma unroll
        for (int off = 32; off > 0; off >>= 1) cnt += __shfl_down(cnt, off, 64);
        if ((t & 63) == 0) part[t >> 6] = cnt;
        __syncthreads();
        if (t == 0) flags[b] = part[0] + part[1] + part[2] + part[3];
    } else {
        int i = (b - 5) * 256 + t;
        if (i <= K) btotal[i] = 0;
    }
}

// ---- prep: blocks [0,nStage) stage S0 + layer-0 gather; rest: bucket count
__global__ __launch_bounds__(PTPB) void k_prep(const void* __restrict__ ue,
                       const void* __restrict__ ie,
                       const void* __restrict__ users, const void* __restrict__ items,
                       const void* __restrict__ edst,
                       ushort4* __restrict__ S, float* __restrict__ out,
                       int* __restrict__ btotal, const int* __restrict__ flags,
                       int NU16, int N16, int B, int NU, int NI,
                       int E, int N, int K, int nStage) {
    if (blockIdx.x < nStage) {
        int tid = blockIdx.x * PTPB + threadIdx.x;
        if (tid < N16) {
            // stage: one ushort4 (4 bf16) per thread
            bool user = tid < NU16;
            const void* src = user ? ue : ie;
            int fl  = user ? flags[0] : flags[1];
            int idx = user ? tid : tid - NU16;
            ushort4 o;
            if (fl > FTHR) {
                o = ((const ushort4*)src)[idx];
            } else {
                float4 v = ((const float4*)src)[idx];
                o.x = f2bf(v.x); o.y = f2bf(v.y); o.z = f2bf(v.z); o.w = f2bf(v.w);
            }
            S[tid] = o;
        } else {
            // layer-0 gather: out[slot] = input emb (f32)
            int g = tid - N16;
            int r = g >> 6, d = g & 63;
            if (r >= 2 * B) return;
            int wide = flags[4] > WTHR;
            const void* src; long long row; int fl;
            if (r < B) { row = clampi(idx_at(users, r, wide), NU); src = ue; fl = flags[0]; }
            else       { row = clampi(idx_at(items, r - B, wide), NI); src = ie; fl = flags[1]; }
            float v;
            if (fl > FTHR) v = bf2f(((const unsigned short*)src)[row * 64 + d]);
            else           v = ((const float*)src)[row * 64 + d];
            out[g] = v;
        }
    } else {
        // count: per-block LDS hist -> global atomic bucket totals (32 iters)
        __shared__ int h[KMAX + 1];
        int t = threadIdx.x;
        for (int i = t; i < K; i += PTPB) h[i] = 0;
        __syncthreads();
        int wide = flags[3] > WTHR;
        int base = (blockIdx.x - nStage) * CCHUNK;
        int lim = min(base + CCHUNK, E);
        for (int i = base + t; i < lim; i += PTPB) {
            int d = clampi(idx_at(edst, i, wide), N);
            atomicAdd(&h[d >> SHIFT], 1);
        }
        __syncthreads();
        for (int i = t; i < K; i += PTPB)
            if (h[i]) atomicAdd(&btotal[i], h[i]);
    }
}

// ---- scanB: bucket starts + init global cursors (1 block, 1024 thr) ----
__global__ __launch_bounds__(SBT) void k_scanB(const int* __restrict__ btotal,
                        int* __restrict__ bucketStart, int* __restrict__ gcur,
                        int* __restrict__ rowstart, int K, int N) {
    __shared__ int sh[SBT];
    int t = threadIdx.x;
    int v = (t < K) ? btotal[t] : 0;
    sh[t] = v;
    for (int off = 1; off < SBT; off <<= 1) {
        __syncthreads();
        int y = (t >= off) ? sh[t - off] : 0;
        __syncthreads();
        sh[t] += y;
    }
    __syncthreads();
    if (t <= K) bucketStart[t] = sh[t] - v;   // exclusive (t=K: v=0 -> total)
    if (t < K)  gcur[t] = sh[t] - v;
    if (t == SBT - 1) rowstart[N] = sh[SBT - 1];  // total edge count
}

// ---- scat: reserve bucket ranges dynamically, LDS-cursor scatter ----
// 1024 thr, SCHUNK 32768 (SPT=32) -> per-bucket runs ~56 edges = 448B.
__global__ __launch_bounds__(CTPB) void k_scat(const void* __restrict__ esrc,
                       const void* __restrict__ edst,
                       const void* __restrict__ eval, const int* __restrict__ flags,
                       int* __restrict__ gcur, unsigned long long* __restrict__ TMP,
                       int E, int N, int K) {
    __shared__ int h[KMAX + 1];
    __shared__ int cur[KMAX + 1];
    int t = threadIdx.x;
    for (int i = t; i < K; i += CTPB) h[i] = 0;
    __syncthreads();
    int wide = flags[3] > WTHR;
    int evalbf = flags[2] > FTHR;
    int base = blockIdx.x * SCHUNK;
    int lim = min(base + SCHUNK, E);
    // pass A: chunk histogram; stash d in registers (static indexing)
    int dstash[SPT];
    #pragma unroll
    for (int j = 0; j < SPT; ++j) {
        int i = base + t + j * CTPB;
        int d = 0;
        if (i < lim) {
            d = clampi(idx_at(edst, i, wide), N);
            atomicAdd(&h[d >> SHIFT], 1);
        }
        dstash[j] = d;
    }
    __syncthreads();
    // reserve contiguous ranges in each touched bucket
    for (int i = t; i < K; i += CTPB)
        if (h[i]) cur[i] = atomicAdd(&gcur[i], h[i]);
    __syncthreads();
    // pass B: scatter via LDS cursors
    #pragma unroll
    for (int j = 0; j < SPT; ++j) {
        int i = base + t + j * CTPB;
        if (i >= lim) continue;
        int d = dstash[j];
        int s = clampi(idx_at(esrc, i, wide), N);
        unsigned short vb = evalbf ? ((const unsigned short*)eval)[i]
                                   : f2bf(((const float*)eval)[i]);
        int b = d >> SHIFT;
        unsigned dl = (unsigned)(d & (BSZ - 1));
        int slot = atomicAdd(&cur[b], 1);
        unsigned long long p = (unsigned long long)(unsigned)s
                             | (((unsigned long long)((dl << 16) | vb)) << 32);
        TMP[slot] = p;
    }
}

// ---- sort pass 2: in-bucket counting sort + rowstart (1 block/bucket, 1024 thr)
// BSZ=512 < STPB=1024: threads t<512 own one hist entry in the scan.
__global__ __launch_bounds__(STPB) void k_p2sort(const unsigned long long* __restrict__ TMP,
                         const int* __restrict__ bucketStart,
                         int2* __restrict__ edges, int* __restrict__ rowstart,
                         int N) {
    __shared__ int hist[BSZ];
    __shared__ int wsum[STPB / 64];
    int b = blockIdx.x;
    int t = threadIdx.x;
    int span0 = bucketStart[b], span1 = bucketStart[b + 1];
    int rbase = b << SHIFT;
    int nrows = min(BSZ, N - rbase);
    for (int i = t; i < BSZ; i += STPB) hist[i] = 0;
    __syncthreads();
    for (int e = span0 + t; e < span1; e += STPB) {
        int dl = (int)((TMP[e] >> 48) & (BSZ - 1));
        atomicAdd(&hist[dl], 1);
    }
    __syncthreads();
    // block-wide exclusive prefix sum over BSZ=512 entries; t<512 participate,
    // all threads hit barriers uniformly.
    int wid = t >> 6, lane = t & 63;
    int v = (t < BSZ) ? hist[t] : 0;
    int x = v;
    #pragma unroll
    for (int off = 1; off < 64; off <<= 1) {
        int y = __shfl_up(x, off, 64);
        if (lane >= off) x += y;
    }
    if (lane == 63) wsum[wid] = x;
    __syncthreads();
    int wbase = 0;
    #pragma unroll
    for (int w = 0; w < STPB / 64; ++w) wbase += (w < wid) ? wsum[w] : 0;
    int texcl = wbase + x - v;     // exclusive prefix for entry t (t<BSZ)
    __syncthreads();
    if (t < BSZ) hist[t] = texcl;
    __syncthreads();
    // rowstart for this bucket's rows
    for (int r = t; r < nrows; r += STPB) rowstart[rbase + r] = span0 + hist[r];
    __syncthreads();
    // scatter to final sorted position (hist doubles as cursor)
    for (int e = span0 + t; e < span1; e += STPB) {
        unsigned long long p = TMP[e];
        int dl = (int)((p >> 48) & (BSZ - 1));
        unsigned vb = (unsigned)((p >> 32) & 0xffffu);
        int src = (int)(unsigned)p;
        int slot = span0 + atomicAdd(&hist[dl], 1);
        edges[slot] = make_int2(src, (int)(vb << 16));
    }
}

// ---- atomic-free SpMM body — k_spmm's private copy (R16 frozen form) ----
template <int U>
__device__ __forceinline__ void spmm_batchA(const unsigned short* __restrict__ Sin,
                                            const int2* __restrict__ edges,
                                            int k, int lane, float& acc) {
    int2 e[U];
    #pragma unroll
    for (int j = 0; j < U; ++j) e[j] = edges[k + j];
    float a[U];
    #pragma unroll
    for (int j = 0; j < U; ++j) a[j] = bf2f(Sin[(size_t)e[j].x * 64 + lane]);
    #pragma unroll
    for (int j = 0; j < U; ++j) acc += __int_as_float(e[j].y) * a[j];
}

// ---- full SpMM: one wave per dst row, lane = dim (FROZEN, do not touch) ----
__global__ void k_spmm(const unsigned short* __restrict__ Sin,
                       unsigned short* __restrict__ Sout,
                       const int* __restrict__ rowstart,
                       const int2* __restrict__ edges, int N) {
    int wid = (blockIdx.x * blockDim.x + threadIdx.x) >> 6;
    int lane = threadIdx.x & 63;
    if (wid >= N) return;
    int start = __builtin_amdgcn_readfirstlane(rowstart[wid]);
    int end   = __builtin_amdgcn_readfirstlane(rowstart[wid + 1]);
    float acc = 0.f;
    int k = start;
    for (; k + 16 <= end; k += 16) spmm_batchA<16>(Sin, edges, k, lane, acc);
    if (k + 8 <= end) { spmm_batchA<8>(Sin, edges, k, lane, acc); k += 8; }
    if (k + 4 <= end) { spmm_batchA<4>(Sin, edges, k, lane, acc); k += 4; }
    if (k + 2 <= end) { spmm_batchA<2>(Sin, edges, k, lane, acc); k += 2; }
    if (k < end)      { spmm_batchA<1>(Sin, edges, k, lane, acc); }
    __builtin_nontemporal_store(f2bf(acc), &Sout[(size_t)wid * 64 + lane]);
}

// ---- k_spmm_b's private copy of the body (codegen isolation) ----
template <int U>
__device__ __forceinline__ void spmm_batchB(const unsigned short* __restrict__ Sin,
                                            const int2* __restrict__ edges,
                                            int k, int lane, float& acc) {
    int2 e[U];
    #pragma unroll
    for (int j = 0; j < U; ++j) e[j] = edges[k + j];
    float a[U];
    #pragma unroll
    for (int j = 0; j < U; ++j) a[j] = bf2f(Sin[(size_t)e[j].x * 64 + lane]);
    #pragma unroll
    for (int j = 0; j < U; ++j) acc += __int_as_float(e[j].y) * a[j];
}

// ---- final layer fused: SpMM only at batch rows, accumulate f32 into out ----
__global__ void k_spmm_b(const unsigned short* __restrict__ Sin,
                         const void* __restrict__ users, const void* __restrict__ items,
                         const int* __restrict__ rowstart, const int2* __restrict__ edges,
                         float* __restrict__ out, const int* __restrict__ flags,
                         int B, int NU, int NI) {
    int tid = blockIdx.x * blockDim.x + threadIdx.x;
    int wid = tid >> 6, lane = threadIdx.x & 63;
    if (wid >= 2 * B) return;
    int wide = flags[4] > WTHR;
    int row;
    if (wid < B) row = clampi(idx_at(users, wid, wide), NU);
    else         row = NU + clampi(idx_at(items, wid - B, wide), NI);
    int start = __builtin_amdgcn_readfirstlane(rowstart[row]);
    int end   = __builtin_amdgcn_readfirstlane(rowstart[row + 1]);
    float acc = 0.f;
    int k = start;
    for (; k + 16 <= end; k += 16) spmm_batchB<16>(Sin, edges, k, lane, acc);
    if (k + 8 <= end) { spmm_batchB<8>(Sin, edges, k, lane, acc); k += 8; }
    if (k + 4 <= end) { spmm_batchB<4>(Sin, edges, k, lane, acc); k += 4; }
    if (k + 2 <= end) { spmm_batchB<2>(Sin, edges, k, lane, acc); k += 2; }
    if (k < end)      { spmm_batchB<1>(Sin, edges, k, lane, acc); }
    out[(size_t)wid * 64 + lane] += acc;
}

// ---- epilogue: add layer1(S1)+layer2(S0) batch rows, scale 1/4, scores ----
__global__ void epilogue(float* __restrict__ out,
                         const unsigned short* __restrict__ S0,
                         const unsigned short* __restrict__ S1,
                         const void* __restrict__ users, const void* __restrict__ items,
                         const int* __restrict__ flags, int B, int NU, int NI) {
    int tid = blockIdx.x * blockDim.x + threadIdx.x;
    int b = tid >> 6, d = tid & 63;
    if (b >= B) return;
    int wide = flags[4] > WTHR;
    long long urow = clampi(idx_at(users, b, wide), NU);
    long long irow = (long long)NU + clampi(idx_at(items, b, wide), NI);
    float u = (out[tid] + bf2f(S1[urow * 64 + d]) + bf2f(S0[urow * 64 + d])) * 0.25f;
    float i = (out[B * 64 + tid] + bf2f(S1[irow * 64 + d]) + bf2f(S0[irow * 64 + d])) * 0.25f;
    out[tid] = u;
    out[B * 64 + tid] = i;
    float p = u * i;
    #pragma unroll
    for (int off = 32; off > 0; off >>= 1) p += __shfl_down(p, off, 64);
    if (d == 0) out[2 * B * 64 + b] = p;
}

__global__ void diag_fill(float* __restrict__ out, int n, float marker) {
    int tid = blockIdx.x * blockDim.x + threadIdx.x;
    if (tid < n) out[tid] = marker;
}

extern "C" void kernel_launch(void* const* d_in, const int* in_sizes, int n_in,
                              void* d_out, int out_size, void* d_ws, size_t ws_size,
                              hipStream_t stream) {
    const void* ue    = d_in[0];
    const void* ie    = d_in[1];
    const void* esrc  = d_in[2];
    const void* edst  = d_in[3];
    const void* eval  = d_in[4];
    const void* users = d_in[5];
    const void* items = d_in[6];
    float* out = (float*)d_out;

    const int TPB = 256;
    if (n_in != 7) {
        diag_fill<<<(out_size + TPB - 1) / TPB, TPB, 0, stream>>>(out, out_size,
                                                                  3000.0f + 64.0f * n_in);
        return;
    }

    const int NU = in_sizes[0] / DIM;
    const int NI = in_sizes[1] / DIM;
    const int N  = NU + NI;
    const int E  = in_sizes[2];
    const int B  = in_sizes[5];
    const int K     = (N + BSZ - 1) >> SHIFT;
    const int NBLKC = (E + CCHUNK - 1) / CCHUNK;   // count blocks
    const int NBLKS = (E + SCHUNK - 1) / SCHUNK;   // scat blocks

    const size_t sBytes   = (size_t)N * DIM * sizeof(unsigned short);
    const size_t tmpBytes = sBytes > (size_t)E * 8 ? sBytes : (size_t)E * 8;
    size_t off = 0;
    auto take = [&](size_t bytes) { size_t o = off; off += (bytes + 255) & ~255ull; return o; };
    char* base = (char*)d_ws;
    unsigned short* S0   = (unsigned short*)(base + take(sBytes));
    unsigned short* S1   = (unsigned short*)(base + take(tmpBytes));   // doubles as TMP
    int2*  edges   = (int2*)(base + take((size_t)E * 8));
    int*   flags   = (int*)(base + take(64));
    int*   btotal  = (int*)(base + take((KMAX + 1) * 4));
    int*   gcur    = (int*)(base + take((KMAX + 1) * 4));
    int*   bucketStart = (int*)(base + take((KMAX + 2) * 4));
    int*   rowstart    = (int*)(base + take((size_t)(N + 1) * 4));
    const size_t need = off;

    if (ws_size < need || K > KMAX) {
        diag_fill<<<(out_size + TPB - 1) / TPB, TPB, 0, stream>>>(out, out_size,
                                                                  1000.0f + (float)(ws_size >> 20));
        return;
    }

    const int N16 = N * 16, NU16 = NU * 16;
    const int nStage = (N16 + 2 * B * 64 + PTPB - 1) / PTPB;
    dim3 gInit(5 + (K + 1 + TPB - 1) / TPB);
    dim3 gPrep(nStage + NBLKC);
    dim3 gBatch((2 * B * 64 + TPB - 1) / TPB);
    dim3 gSpmm(((size_t)N * 64 + TPB - 1) / TPB);
    dim3 gEpi((B * 64 + TPB - 1) / TPB);

    // 1: sniff + zero btotal
    k_init<<<gInit, TPB, 0, stream>>>((const unsigned*)ue, (const unsigned*)ie,
                                      (const unsigned*)eval, (const unsigned*)esrc,
                                      (const unsigned*)users, flags, btotal, K);
    // 2: stage S0 + layer-0 gather || bucket count (512 thr, 16K chunks)
    k_prep<<<gPrep, PTPB, 0, stream>>>(ue, ie, users, items, edst, (ushort4*)S0, out,
                                       btotal, flags, NU16, N16, B, NU, NI, E, N, K,
                                       nStage);
    // 3-5: scan -> reserve+scatter (1024 thr, 32K chunks) -> in-bucket sort
    k_scanB<<<1, SBT, 0, stream>>>(btotal, bucketStart, gcur, rowstart, K, N);
    k_scat<<<NBLKS, CTPB, 0, stream>>>(esrc, edst, eval, flags, gcur,
                                       (unsigned long long*)S1, E, N, K);
    k_p2sort<<<K, STPB, 0, stream>>>((const unsigned long long*)S1, bucketStart,
                                     edges, rowstart, N);

    // 6-8: layers 1,2 full SpMM; layer 3 batch-row SpMM
    k_spmm<<<gSpmm, TPB, 0, stream>>>(S0, S1, rowstart, edges, N);
    k_spmm<<<gSpmm, TPB, 0, stream>>>(S1, S0, rowstart, edges, N);
    k_spmm_b<<<gBatch, TPB, 0, stream>>>(S0, users, items, rowstart, edges, out, flags,
                                         B, NU, NI);
    // 9: epilogue folds layer1 (S1) + layer2 (S0) batch accumulation + scores
    epilogue<<<gEpi, TPB, 0, stream>>>(out, S0, S1, users, items, flags, B, NU, NI);
}